// Round 5
// baseline (206.507 us; speedup 1.0000x reference)
//
#include <hip/hip_runtime.h>

typedef unsigned short u16;
typedef unsigned int u32;
typedef short bf16x8 __attribute__((ext_vector_type(8)));
typedef float f32x4 __attribute__((ext_vector_type(4)));

#define MFMA16(a, b, c) __builtin_amdgcn_mfma_f32_16x16x32_bf16((a), (b), (c), 0, 0, 0)

__device__ __forceinline__ u16 f2bf(float f) {
  u32 u = __builtin_bit_cast(u32, f);
  u += 0x7FFFu + ((u >> 16) & 1u);
  return (u16)(u >> 16);
}
// packed f32x2 -> bf16x2 (round-nearest-even); HW inst on gfx950
__device__ __forceinline__ u32 pk2bf(float a, float b) {
#if __has_builtin(__builtin_amdgcn_cvt_pk_bf16_f32)
  auto v = __builtin_amdgcn_cvt_pk_bf16_f32(a, b);
  return __builtin_bit_cast(u32, v);
#else
  return (u32)f2bf(a) | ((u32)f2bf(b) << 16);
#endif
}

// ws byte offsets
#define WS_MGF   0         // bf16 [8 jt][64 lane][8 j]        B-frags of M^T   (8192 B)
#define WS_WT1F  8192      // bf16 [8 ot][8 ks][64][8]         B-frags of Wp1   (65536 B)
#define WS_WT2F  73728     // bf16 [8 mt][2 h][8 ks][64][8]    A-frags of Wp2^T (131072 B)
#define WS_B1    204800    // f32 [128]  bias1 + T0-fold
#define WS_B2    205312    // f32 [128]  bias2 + T0-fold

__global__ void prep_kernel(const float* __restrict__ adj,
                            const float* __restrict__ adj_bias,
                            const float* __restrict__ w1,
                            const float* __restrict__ b1,
                            const float* __restrict__ w2,
                            const float* __restrict__ b2,
                            char* __restrict__ ws) {
  const int tid = threadIdx.x;
  if (blockIdx.x == 0) {
    __shared__ float sa[1024], Ls[1024], L2s[1024], L3s[1024], sdre[32];
    float bias = adj_bias[0];
    for (int i = tid; i < 1024; i += 256) sa[i] = fmaxf(adj[i] + bias, 0.0f);
    __syncthreads();
    if (tid < 32) {
      float s = 0.0f;
      for (int c = 0; c < 32; ++c) s += sa[tid * 32 + c];
      sdre[tid] = 1.0f / sqrtf(s + 1e-5f);
    }
    __syncthreads();
    for (int i = tid; i < 1024; i += 256) {
      int n = i >> 5, c = i & 31;
      Ls[i] = (n == c ? 1.0f : 0.0f) - sdre[n] * sa[i] * sdre[c];
    }
    __syncthreads();
    for (int i = tid; i < 1024; i += 256) {
      int r = i >> 5, c = i & 31;
      float s = 0.0f;
      for (int m = 0; m < 32; ++m) s += Ls[r * 32 + m] * Ls[m * 32 + c];
      L2s[i] = s;
    }
    __syncthreads();
    for (int i = tid; i < 1024; i += 256) {
      int r = i >> 5, c = i & 31;
      float s = 0.0f;
      for (int m = 0; m < 32; ++m) s += L2s[r * 32 + m] * Ls[m * 32 + c];
      L3s[i] = s;
    }
    __syncthreads();
    // M stacked [128x32]: rows 0-31 I, 32-63 L, 64-95 2L^2-I, 96-127 4L^3-3L.
    // B-fragments of M^T: MGf[jt][lane][j] = M[col=jt*16+(lane&15)][k=(lane>>4)*8+j]
    u16* MGf = (u16*)(ws + WS_MGF);
    for (int i = tid; i < 4096; i += 256) {
      int jt = i >> 9, lane = (i >> 3) & 63, j = i & 7;
      int col = jt * 16 + (lane & 15);
      int k = ((lane >> 4) << 3) + j;
      int kk = col >> 5, np = col & 31;
      float v;
      if (kk == 0)      v = (np == k) ? 1.0f : 0.0f;
      else if (kk == 1) v = Ls[np * 32 + k];
      else if (kk == 2) v = 2.0f * L2s[np * 32 + k] - (np == k ? 1.0f : 0.0f);
      else              v = 4.0f * L3s[np * 32 + k] - 3.0f * Ls[np * 32 + k];
      MGf[i] = f2bf(v);
    }
    // biases with T0(=ones) term folded in
    float* B1 = (float*)(ws + WS_B1);
    float* B2 = (float*)(ws + WS_B2);
    if (tid < 128) {
      float s = b1[tid];
      for (int c = 0; c < 60; ++c) s += w1[(c * 5) * 128 + tid];
      B1[tid] = s;
    } else {
      int o = tid - 128;
      float s = b2[o];
      for (int c = 0; c < 128; ++c) s += w2[(c * 5) * 128 + o];
      B2[o] = s;
    }
  } else {
    u16* WT1F = (u16*)(ws + WS_WT1F);
    u16* WT2F = (u16*)(ws + WS_WT2F);
    int g = (blockIdx.x - 1) * 256 + tid;
    // WT1F: kc = k*64 + c (c padded 60->64)
    for (int i = g; i < 32768; i += 16 * 256) {
      int ot = i >> 12, ks = (i >> 9) & 7, lane = (i >> 3) & 63, j = i & 7;
      int o = ot * 16 + (lane & 15);
      int kc = ks * 32 + ((lane >> 4) << 3) + j;
      int k = kc >> 6, c = kc & 63;
      WT1F[i] = (c < 60) ? f2bf(w1[(c * 5 + k + 1) * 128 + o]) : (u16)0;
    }
    // WT2F: A-frags of Wp2^T in half-interleaved kc order:
    // kc = (ks>>1)*128 + (ks&1)*32 + h*64 + q*8 + j, with kc = k*128 + c
    for (int i = g; i < 65536; i += 16 * 256) {
      int mt = i >> 13, h = (i >> 12) & 1, ks = (i >> 9) & 7;
      int lane = (i >> 3) & 63, j = i & 7;
      int kc = ((ks >> 1) << 7) + ((ks & 1) << 5) + (h << 6) + (((lane >> 4)) << 3) + j;
      int k = kc >> 7, c = kc & 127;
      int o = (mt << 4) + (lane & 15);
      WT2F[i] = f2bf(w2[(c * 5 + k + 1) * 128 + o]);
    }
  }
}

__global__ __launch_bounds__(256, 3) void dgcnn_kernel(
    const float* __restrict__ x,
    const char* __restrict__ ws,
    const float* __restrict__ fc_w,
    const float* __restrict__ fc_b,
    float* __restrict__ out) {
  // LDS arena (phase-aliased), 26.5 KB:
  //   Xt [64][40]  bf16 @0      (5120)   x^T, rows 60..63 zeroed
  //   Ht [128][40] bf16 @0      (10240)  layer1 out^T (over dead Xt)
  //   Y  [32][264] bf16 @10240  (16896)  cheb terms: Y1 full (layer1) / Y2 halves (layer2)
  __shared__ __align__(16) char arena[27136];
  __shared__ float red[8];
  u16* Xt = (u16*)arena;
  u16* Ht = (u16*)arena;
  u16* Y  = (u16*)(arena + 10240);

  const u16* MGf  = (const u16*)(ws + WS_MGF);
  const u16* WT1F = (const u16*)(ws + WS_WT1F);
  const u16* WT2F = (const u16*)(ws + WS_WT2F);
  const float* bias1 = (const float*)(ws + WS_B1);
  const float* bias2 = (const float*)(ws + WS_B2);

  const int tid = threadIdx.x;
  const int w = tid >> 6, lane = tid & 63;
  const int l15 = lane & 15, q = lane >> 4;
  const int b = blockIdx.x;
  const f32x4 z4 = {0.0f, 0.0f, 0.0f, 0.0f};

  // ---- deep prefetch: M^T frags + ALL einsum1 weight frags (consumed 2-3 phases later)
  bf16x8 mB0 = *(const bf16x8*)(MGf + ((2 * w + 0) * 64 + lane) * 8);
  bf16x8 mB1 = *(const bf16x8*)(MGf + ((2 * w + 1) * 64 + lane) * 8);
  bf16x8 wf1[16];
#pragma unroll
  for (int ot = 0; ot < 2; ++ot)
#pragma unroll
    for (int ks = 0; ks < 8; ++ks)
      wf1[ot * 8 + ks] = *(const bf16x8*)(WT1F + (((2 * w + ot) * 8 + ks) * 64 + lane) * 8);

  // zero pad rows 60..63 of Xt
  for (int i = tid; i < 160; i += 256) Xt[(60 + (i / 40)) * 40 + (i % 40)] = 0;
  const float* xb = x + (size_t)b * 1920;
  for (int i = tid; i < 1920; i += 256) {
    int n = i / 60, c = i - n * 60;
    Xt[c * 40 + n] = f2bf(xb[i]);
  }
  __syncthreads();

  // ---- L1-G1: Y1^T = X^T @ M^T  (Xt and Y regions disjoint -> no mid barrier) ----
  {
    f32x4 acc[4][2];
#pragma unroll
    for (int mt = 0; mt < 4; ++mt) {
      bf16x8 aX = *(const bf16x8*)&Xt[(mt * 16 + l15) * 40 + q * 8];
      acc[mt][0] = MFMA16(aX, mB0, z4);
      acc[mt][1] = MFMA16(aX, mB1, z4);
    }
#pragma unroll
    for (int mt = 0; mt < 4; ++mt)
#pragma unroll
      for (int jt = 0; jt < 2; ++jt) {
        int np = jt * 16 + l15;
        uint2 vv;
        vv.x = pk2bf(acc[mt][jt][0], acc[mt][jt][1]);
        vv.y = pk2bf(acc[mt][jt][2], acc[mt][jt][3]);
        *(uint2*)&Y[np * 264 + w * 64 + mt * 16 + q * 4] = vv;
      }
  }
  __syncthreads();

  // ---- einsum1: H[n][o] = Y1[n][kc] @ Wp1[kc][o], +bias relu -> Ht[o][n] ----
  {
    f32x4 acc[2][2] = {{z4, z4}, {z4, z4}};
#pragma unroll
    for (int ks = 0; ks < 8; ++ks) {
      bf16x8 a0 = *(const bf16x8*)&Y[(l15) * 264 + ks * 32 + q * 8];
      bf16x8 a1 = *(const bf16x8*)&Y[(16 + l15) * 264 + ks * 32 + q * 8];
      acc[0][0] = MFMA16(a0, wf1[ks], acc[0][0]);
      acc[0][1] = MFMA16(a0, wf1[8 + ks], acc[0][1]);
      acc[1][0] = MFMA16(a1, wf1[ks], acc[1][0]);
      acc[1][1] = MFMA16(a1, wf1[8 + ks], acc[1][1]);
    }
#pragma unroll
    for (int ot = 0; ot < 2; ++ot) {
      int o = (2 * w + ot) * 16 + l15;
      float bv = bias1[o];
#pragma unroll
      for (int mt = 0; mt < 2; ++mt) {
        uint2 vv;
        vv.x = pk2bf(fmaxf(acc[mt][ot][0] + bv, 0.0f), fmaxf(acc[mt][ot][1] + bv, 0.0f));
        vv.y = pk2bf(fmaxf(acc[mt][ot][2] + bv, 0.0f), fmaxf(acc[mt][ot][3] + bv, 0.0f));
        *(uint2*)&Ht[o * 40 + mt * 16 + q * 4] = vv;
      }
    }
  }
  __syncthreads();

  // ---- layer 2 in two o1-halves; einsum2 accumulates across halves in regs ----
  f32x4 acc2[2][2] = {{z4, z4}, {z4, z4}};  // [ot][nt]
#pragma unroll
  for (int h = 0; h < 2; ++h) {
    // prefetch this half's einsum2 weight frags; loads overlap L2-G1 compute below
    bf16x8 wf2[16];
#pragma unroll
    for (int ot = 0; ot < 2; ++ot)
#pragma unroll
      for (int ks = 0; ks < 8; ++ks)
        wf2[ot * 8 + ks] =
            *(const bf16x8*)(WT2F + ((((2 * w + ot) * 2 + h) * 8 + ks) * 64 + lane) * 8);

    // L2-G1 half: Y2h^T = H^T(rows 64h..64h+63) @ M^T
    {
      f32x4 acc[4][2];
#pragma unroll
      for (int mtl = 0; mtl < 4; ++mtl) {
        int mt = 4 * h + mtl;
        bf16x8 aH = *(const bf16x8*)&Ht[(mt * 16 + l15) * 40 + q * 8];
        acc[mtl][0] = MFMA16(aH, mB0, z4);
        acc[mtl][1] = MFMA16(aH, mB1, z4);
      }
#pragma unroll
      for (int mtl = 0; mtl < 4; ++mtl)
#pragma unroll
        for (int jt = 0; jt < 2; ++jt) {
          int np = jt * 16 + l15;
          uint2 vv;
          vv.x = pk2bf(acc[mtl][jt][0], acc[mtl][jt][1]);
          vv.y = pk2bf(acc[mtl][jt][2], acc[mtl][jt][3]);
          *(uint2*)&Y[np * 264 + w * 64 + mtl * 16 + q * 4] = vv;
        }
    }
    __syncthreads();
    // einsum2 partial (flipped): D[o][n] += Wp2^T[o][kc in half] @ Y2h^T[kc][n]
#pragma unroll
    for (int ks = 0; ks < 8; ++ks) {
      bf16x8 by0 = *(const bf16x8*)&Y[(l15) * 264 + ks * 32 + q * 8];
      bf16x8 by1 = *(const bf16x8*)&Y[(16 + l15) * 264 + ks * 32 + q * 8];
      acc2[0][0] = MFMA16(wf2[ks], by0, acc2[0][0]);
      acc2[0][1] = MFMA16(wf2[ks], by1, acc2[0][1]);
      acc2[1][0] = MFMA16(wf2[8 + ks], by0, acc2[1][0]);
      acc2[1][1] = MFMA16(wf2[8 + ks], by1, acc2[1][1]);
    }
    __syncthreads();  // h=0: Y reads done before next half overwrites; h=1: before red[]
  }

  // ---- epilogue: bias2+relu in regs, fc directly from accumulators ----
  float p0 = 0.0f, p1 = 0.0f;
#pragma unroll
  for (int ot = 0; ot < 2; ++ot) {
    int ob = (2 * w + ot) * 16 + q * 4;  // o base, 4 contiguous per lane
    float4 bv = *(const float4*)&bias2[ob];
#pragma unroll
    for (int nt = 0; nt < 2; ++nt) {
      int n = nt * 16 + l15;
      float h0 = fmaxf(acc2[ot][nt][0] + bv.x, 0.0f);
      float h1 = fmaxf(acc2[ot][nt][1] + bv.y, 0.0f);
      float h2 = fmaxf(acc2[ot][nt][2] + bv.z, 0.0f);
      float h3 = fmaxf(acc2[ot][nt][3] + bv.w, 0.0f);
      float4 w0 = *(const float4*)&fc_w[n * 128 + ob];
      float4 w1v = *(const float4*)&fc_w[4096 + n * 128 + ob];
      p0 = fmaf(h0, w0.x, fmaf(h1, w0.y, fmaf(h2, w0.z, fmaf(h3, w0.w, p0))));
      p1 = fmaf(h0, w1v.x, fmaf(h1, w1v.y, fmaf(h2, w1v.z, fmaf(h3, w1v.w, p1))));
    }
  }
#pragma unroll
  for (int off = 32; off >= 1; off >>= 1) {
    p0 += __shfl_xor(p0, off);
    p1 += __shfl_xor(p1, off);
  }
  if (lane == 0) {
    red[w * 2 + 0] = p0;
    red[w * 2 + 1] = p1;
  }
  __syncthreads();
  if (tid < 2) {
    out[b * 2 + tid] = red[tid] + red[2 + tid] + red[4 + tid] + red[6 + tid] + fc_b[tid];
  }
}

extern "C" void kernel_launch(void* const* d_in, const int* in_sizes, int n_in,
                              void* d_out, int out_size, void* d_ws, size_t ws_size,
                              hipStream_t stream) {
  const float* x        = (const float*)d_in[0];
  const float* adj      = (const float*)d_in[1];
  const float* adj_bias = (const float*)d_in[2];
  const float* w1       = (const float*)d_in[3];
  const float* b1       = (const float*)d_in[4];
  const float* w2       = (const float*)d_in[5];
  const float* b2       = (const float*)d_in[6];
  const float* fc_w     = (const float*)d_in[7];
  const float* fc_b     = (const float*)d_in[8];
  float* out = (float*)d_out;
  char* ws   = (char*)d_ws;

  prep_kernel<<<17, 256, 0, stream>>>(adj, adj_bias, w1, b1, w2, b2, ws);
  dgcnn_kernel<<<8192, 256, 0, stream>>>(x, ws, fc_w, fc_b, out);
}

// Round 6
// 203.249 us; speedup vs baseline: 1.0160x; 1.0160x over previous
//
#include <hip/hip_runtime.h>

typedef unsigned short u16;
typedef unsigned int u32;
typedef short bf16x8 __attribute__((ext_vector_type(8)));
typedef float f32x4 __attribute__((ext_vector_type(4)));

#define MFMA16(a, b, c) __builtin_amdgcn_mfma_f32_16x16x32_bf16((a), (b), (c), 0, 0, 0)

__device__ __forceinline__ u16 f2bf(float f) {
  u32 u = __builtin_bit_cast(u32, f);
  u += 0x7FFFu + ((u >> 16) & 1u);
  return (u16)(u >> 16);
}
__device__ __forceinline__ u32 pk2bf(float a, float b) {
#if __has_builtin(__builtin_amdgcn_cvt_pk_bf16_f32)
  auto v = __builtin_amdgcn_cvt_pk_bf16_f32(a, b);
  return __builtin_bit_cast(u32, v);
#else
  return (u32)f2bf(a) | ((u32)f2bf(b) << 16);
#endif
}

// ws byte offsets
#define WS_MGF   0         // bf16 [8 jt][64 lane][8 j]        B-frags of M^T   (8192 B)
#define WS_WT1F  8192      // bf16 [8 ot][8 ks][64][8]         B-frags of Wp1   (65536 B)
#define WS_WT2F  73728     // bf16 [8 mt][2 h][8 ks][64][8]    A-frags of Wp2^T (131072 B)
#define WS_B1    204800    // f32 [128]  bias1 + T0-fold
#define WS_B2    205312    // f32 [128]  bias2 + T0-fold

__global__ void prep_kernel(const float* __restrict__ adj,
                            const float* __restrict__ adj_bias,
                            const float* __restrict__ w1,
                            const float* __restrict__ b1,
                            const float* __restrict__ w2,
                            const float* __restrict__ b2,
                            char* __restrict__ ws) {
  const int tid = threadIdx.x;
  if (blockIdx.x == 0) {
    __shared__ float sa[1024], Ls[1024], L2s[1024], L3s[1024], sdre[32];
    float bias = adj_bias[0];
    for (int i = tid; i < 1024; i += 256) sa[i] = fmaxf(adj[i] + bias, 0.0f);
    __syncthreads();
    if (tid < 32) {
      float s = 0.0f;
      for (int c = 0; c < 32; ++c) s += sa[tid * 32 + c];
      sdre[tid] = 1.0f / sqrtf(s + 1e-5f);
    }
    __syncthreads();
    for (int i = tid; i < 1024; i += 256) {
      int n = i >> 5, c = i & 31;
      Ls[i] = (n == c ? 1.0f : 0.0f) - sdre[n] * sa[i] * sdre[c];
    }
    __syncthreads();
    for (int i = tid; i < 1024; i += 256) {
      int r = i >> 5, c = i & 31;
      float s = 0.0f;
      for (int m = 0; m < 32; ++m) s += Ls[r * 32 + m] * Ls[m * 32 + c];
      L2s[i] = s;
    }
    __syncthreads();
    for (int i = tid; i < 1024; i += 256) {
      int r = i >> 5, c = i & 31;
      float s = 0.0f;
      for (int m = 0; m < 32; ++m) s += L2s[r * 32 + m] * Ls[m * 32 + c];
      L3s[i] = s;
    }
    __syncthreads();
    // M stacked [128x32]: rows 0-31 I, 32-63 L, 64-95 2L^2-I, 96-127 4L^3-3L.
    // B-fragments of M^T: MGf[jt][lane][j] = M[col=jt*16+(lane&15)][k=(lane>>4)*8+j]
    u16* MGf = (u16*)(ws + WS_MGF);
    for (int i = tid; i < 4096; i += 256) {
      int jt = i >> 9, lane = (i >> 3) & 63, j = i & 7;
      int col = jt * 16 + (lane & 15);
      int k = ((lane >> 4) << 3) + j;
      int kk = col >> 5, np = col & 31;
      float v;
      if (kk == 0)      v = (np == k) ? 1.0f : 0.0f;
      else if (kk == 1) v = Ls[np * 32 + k];
      else if (kk == 2) v = 2.0f * L2s[np * 32 + k] - (np == k ? 1.0f : 0.0f);
      else              v = 4.0f * L3s[np * 32 + k] - 3.0f * Ls[np * 32 + k];
      MGf[i] = f2bf(v);
    }
    float* B1 = (float*)(ws + WS_B1);
    float* B2 = (float*)(ws + WS_B2);
    if (tid < 128) {
      float s = b1[tid];
      for (int c = 0; c < 60; ++c) s += w1[(c * 5) * 128 + tid];
      B1[tid] = s;
    } else {
      int o = tid - 128;
      float s = b2[o];
      for (int c = 0; c < 128; ++c) s += w2[(c * 5) * 128 + o];
      B2[o] = s;
    }
  } else {
    u16* WT1F = (u16*)(ws + WS_WT1F);
    u16* WT2F = (u16*)(ws + WS_WT2F);
    int g = (blockIdx.x - 1) * 256 + tid;
    // WT1F: kc = k*64 + c (c padded 60->64)
    for (int i = g; i < 32768; i += 16 * 256) {
      int ot = i >> 12, ks = (i >> 9) & 7, lane = (i >> 3) & 63, j = i & 7;
      int o = ot * 16 + (lane & 15);
      int kc = ks * 32 + ((lane >> 4) << 3) + j;
      int k = kc >> 6, c = kc & 63;
      WT1F[i] = (c < 60) ? f2bf(w1[(c * 5 + k + 1) * 128 + o]) : (u16)0;
    }
    // WT2F: A-frags of Wp2^T, half-interleaved kc order:
    // kc = (ks>>1)*128 + (ks&1)*32 + h*64 + q*8 + j, with kc = k*128 + c
    for (int i = g; i < 65536; i += 16 * 256) {
      int mt = i >> 13, h = (i >> 12) & 1, ks = (i >> 9) & 7;
      int lane = (i >> 3) & 63, j = i & 7;
      int kc = ((ks >> 1) << 7) + ((ks & 1) << 5) + (h << 6) + (((lane >> 4)) << 3) + j;
      int k = kc >> 7, c = kc & 127;
      int o = (mt << 4) + (lane & 15);
      WT2F[i] = f2bf(w2[(c * 5 + k + 1) * 128 + o]);
    }
  }
}

__global__ __launch_bounds__(256, 3) void dgcnn_kernel(
    const float* __restrict__ x,
    const char* __restrict__ ws,
    const float* __restrict__ fc_w,
    const float* __restrict__ fc_b,
    float* __restrict__ out) {
  // 2 batches per block. LDS arena (phase-aliased), 52.3 KB -> 3 blocks/CU:
  //   XtA [64][40] bf16 @0, XtB @5120          (x^T, rows 60..63 zeroed)
  //   HtA [128][36] bf16 @0, HtB @9216         (layer1 out^T, over dead Xt)
  //   YA  [32][264] bf16 @18432, YB @35328     (cheb terms)
  __shared__ __align__(16) char arena[52224];
  __shared__ float red[16];
  u16* XtA = (u16*)arena;
  u16* XtB = (u16*)(arena + 5120);
  u16* HtA = (u16*)arena;
  u16* HtB = (u16*)(arena + 9216);
  u16* YA  = (u16*)(arena + 18432);
  u16* YB  = (u16*)(arena + 35328);

  const u16* MGf  = (const u16*)(ws + WS_MGF);
  const u16* WT1F = (const u16*)(ws + WS_WT1F);
  const u16* WT2F = (const u16*)(ws + WS_WT2F);
  const float* bias1 = (const float*)(ws + WS_B1);
  const float* bias2 = (const float*)(ws + WS_B2);

  const int tid = threadIdx.x;
  const int w = tid >> 6, lane = tid & 63;
  const int l15 = lane & 15, q = lane >> 4;
  const int b0 = blockIdx.x * 2;
  const f32x4 z4 = {0.0f, 0.0f, 0.0f, 0.0f};

  // M^T B-fragments (reused in L1-G1 and L2-G1, both batches)
  bf16x8 mB0 = *(const bf16x8*)(MGf + ((2 * w + 0) * 64 + lane) * 8);
  bf16x8 mB1 = *(const bf16x8*)(MGf + ((2 * w + 1) * 64 + lane) * 8);

  // zero pad rows 60..63 of both Xt
  for (int i = tid; i < 160; i += 256) {
    int r = 60 + i / 40, c = i % 40;
    XtA[r * 40 + c] = 0;
    XtB[r * 40 + c] = 0;
  }
  const float* xb = x + (size_t)b0 * 1920;
  for (int i = tid; i < 1920; i += 256) {
    int n = i / 60, c = i - n * 60;
    XtA[c * 40 + n] = f2bf(xb[i]);
    XtB[c * 40 + n] = f2bf(xb[1920 + i]);
  }
  __syncthreads();

  // ---- L1-G1 (both batches): Y1^T = X^T @ M^T ----
  {
    f32x4 accA[4][2], accB[4][2];
#pragma unroll
    for (int mt = 0; mt < 4; ++mt) {
      bf16x8 aXA = *(const bf16x8*)&XtA[(mt * 16 + l15) * 40 + q * 8];
      bf16x8 aXB = *(const bf16x8*)&XtB[(mt * 16 + l15) * 40 + q * 8];
      accA[mt][0] = MFMA16(aXA, mB0, z4);
      accA[mt][1] = MFMA16(aXA, mB1, z4);
      accB[mt][0] = MFMA16(aXB, mB0, z4);
      accB[mt][1] = MFMA16(aXB, mB1, z4);
    }
#pragma unroll
    for (int mt = 0; mt < 4; ++mt)
#pragma unroll
      for (int jt = 0; jt < 2; ++jt) {
        int np = jt * 16 + l15;
        int off = np * 264 + w * 64 + mt * 16 + q * 4;
        uint2 vA, vB;
        vA.x = pk2bf(accA[mt][jt][0], accA[mt][jt][1]);
        vA.y = pk2bf(accA[mt][jt][2], accA[mt][jt][3]);
        vB.x = pk2bf(accB[mt][jt][0], accB[mt][jt][1]);
        vB.y = pk2bf(accB[mt][jt][2], accB[mt][jt][3]);
        *(uint2*)&YA[off] = vA;
        *(uint2*)&YB[off] = vB;
      }
  }
  __syncthreads();

  // ---- einsum1 (both): H[n][o] = Y1[n][kc] @ Wp1[kc][o], +bias relu -> Ht[o][n] ----
  {
    f32x4 accA[2][2] = {{z4, z4}, {z4, z4}};
    f32x4 accB[2][2] = {{z4, z4}, {z4, z4}};
#pragma unroll
    for (int ks = 0; ks < 8; ++ks) {
      bf16x8 wfa = *(const bf16x8*)(WT1F + (((2 * w + 0) * 8 + ks) * 64 + lane) * 8);
      bf16x8 wfb = *(const bf16x8*)(WT1F + (((2 * w + 1) * 8 + ks) * 64 + lane) * 8);
      int offY = ks * 32 + q * 8;
      bf16x8 a0A = *(const bf16x8*)&YA[(l15) * 264 + offY];
      bf16x8 a1A = *(const bf16x8*)&YA[(16 + l15) * 264 + offY];
      bf16x8 a0B = *(const bf16x8*)&YB[(l15) * 264 + offY];
      bf16x8 a1B = *(const bf16x8*)&YB[(16 + l15) * 264 + offY];
      accA[0][0] = MFMA16(a0A, wfa, accA[0][0]);
      accA[0][1] = MFMA16(a0A, wfb, accA[0][1]);
      accA[1][0] = MFMA16(a1A, wfa, accA[1][0]);
      accA[1][1] = MFMA16(a1A, wfb, accA[1][1]);
      accB[0][0] = MFMA16(a0B, wfa, accB[0][0]);
      accB[0][1] = MFMA16(a0B, wfb, accB[0][1]);
      accB[1][0] = MFMA16(a1B, wfa, accB[1][0]);
      accB[1][1] = MFMA16(a1B, wfb, accB[1][1]);
    }
#pragma unroll
    for (int ot = 0; ot < 2; ++ot) {
      int o = (2 * w + ot) * 16 + l15;
      float bv = bias1[o];
#pragma unroll
      for (int mt = 0; mt < 2; ++mt) {
        int off = o * 36 + mt * 16 + q * 4;
        uint2 vA, vB;
        vA.x = pk2bf(fmaxf(accA[mt][ot][0] + bv, 0.0f), fmaxf(accA[mt][ot][1] + bv, 0.0f));
        vA.y = pk2bf(fmaxf(accA[mt][ot][2] + bv, 0.0f), fmaxf(accA[mt][ot][3] + bv, 0.0f));
        vB.x = pk2bf(fmaxf(accB[mt][ot][0] + bv, 0.0f), fmaxf(accB[mt][ot][1] + bv, 0.0f));
        vB.y = pk2bf(fmaxf(accB[mt][ot][2] + bv, 0.0f), fmaxf(accB[mt][ot][3] + bv, 0.0f));
        *(uint2*)&HtA[off] = vA;
        *(uint2*)&HtB[off] = vB;
      }
    }
  }
  __syncthreads();

  // ---- layer 2 in two o1-halves; einsum2 accumulates across halves in regs ----
  f32x4 acc2A[2][2] = {{z4, z4}, {z4, z4}};
  f32x4 acc2B[2][2] = {{z4, z4}, {z4, z4}};
#pragma unroll
  for (int h = 0; h < 2; ++h) {
    // this half's einsum2 weight frags (shared by both batches)
    bf16x8 wf2[16];
#pragma unroll
    for (int ot = 0; ot < 2; ++ot)
#pragma unroll
      for (int ks = 0; ks < 8; ++ks)
        wf2[ot * 8 + ks] =
            *(const bf16x8*)(WT2F + ((((2 * w + ot) * 2 + h) * 8 + ks) * 64 + lane) * 8);

    // L2-G1 half (both): Y2h^T = H^T(rows 64h..64h+63) @ M^T
    {
      f32x4 accA[4][2], accB[4][2];
#pragma unroll
      for (int mtl = 0; mtl < 4; ++mtl) {
        int r = ((4 * h + mtl) * 16 + l15) * 36 + q * 8;
        bf16x8 aHA = *(const bf16x8*)&HtA[r];
        bf16x8 aHB = *(const bf16x8*)&HtB[r];
        accA[mtl][0] = MFMA16(aHA, mB0, z4);
        accA[mtl][1] = MFMA16(aHA, mB1, z4);
        accB[mtl][0] = MFMA16(aHB, mB0, z4);
        accB[mtl][1] = MFMA16(aHB, mB1, z4);
      }
#pragma unroll
      for (int mtl = 0; mtl < 4; ++mtl)
#pragma unroll
        for (int jt = 0; jt < 2; ++jt) {
          int np = jt * 16 + l15;
          int off = np * 264 + w * 64 + mtl * 16 + q * 4;
          uint2 vA, vB;
          vA.x = pk2bf(accA[mtl][jt][0], accA[mtl][jt][1]);
          vA.y = pk2bf(accA[mtl][jt][2], accA[mtl][jt][3]);
          vB.x = pk2bf(accB[mtl][jt][0], accB[mtl][jt][1]);
          vB.y = pk2bf(accB[mtl][jt][2], accB[mtl][jt][3]);
          *(uint2*)&YA[off] = vA;
          *(uint2*)&YB[off] = vB;
        }
    }
    __syncthreads();
    // einsum2 partial (flipped): D[o][n] += Wp2^T[o][kc in half] @ Y2h^T[kc][n]
#pragma unroll
    for (int ks = 0; ks < 8; ++ks) {
      int offY = ks * 32 + q * 8;
      bf16x8 by0A = *(const bf16x8*)&YA[(l15) * 264 + offY];
      bf16x8 by1A = *(const bf16x8*)&YA[(16 + l15) * 264 + offY];
      bf16x8 by0B = *(const bf16x8*)&YB[(l15) * 264 + offY];
      bf16x8 by1B = *(const bf16x8*)&YB[(16 + l15) * 264 + offY];
      acc2A[0][0] = MFMA16(wf2[ks], by0A, acc2A[0][0]);
      acc2A[0][1] = MFMA16(wf2[ks], by1A, acc2A[0][1]);
      acc2A[1][0] = MFMA16(wf2[8 + ks], by0A, acc2A[1][0]);
      acc2A[1][1] = MFMA16(wf2[8 + ks], by1A, acc2A[1][1]);
      acc2B[0][0] = MFMA16(wf2[ks], by0B, acc2B[0][0]);
      acc2B[0][1] = MFMA16(wf2[ks], by1B, acc2B[0][1]);
      acc2B[1][0] = MFMA16(wf2[8 + ks], by0B, acc2B[1][0]);
      acc2B[1][1] = MFMA16(wf2[8 + ks], by1B, acc2B[1][1]);
    }
    __syncthreads();  // h=0: Y reads done before overwrite; h=1: before red[]
  }

  // ---- epilogue: bias2+relu in regs, fc directly from accumulators ----
  float p0A = 0.0f, p1A = 0.0f, p0B = 0.0f, p1B = 0.0f;
#pragma unroll
  for (int ot = 0; ot < 2; ++ot) {
    int ob = (2 * w + ot) * 16 + q * 4;  // o base, 4 contiguous per lane
    float4 bv = *(const float4*)&bias2[ob];
#pragma unroll
    for (int nt = 0; nt < 2; ++nt) {
      int n = nt * 16 + l15;
      float4 w0 = *(const float4*)&fc_w[n * 128 + ob];
      float4 w1v = *(const float4*)&fc_w[4096 + n * 128 + ob];
      float hA0 = fmaxf(acc2A[ot][nt][0] + bv.x, 0.0f);
      float hA1 = fmaxf(acc2A[ot][nt][1] + bv.y, 0.0f);
      float hA2 = fmaxf(acc2A[ot][nt][2] + bv.z, 0.0f);
      float hA3 = fmaxf(acc2A[ot][nt][3] + bv.w, 0.0f);
      float hB0 = fmaxf(acc2B[ot][nt][0] + bv.x, 0.0f);
      float hB1 = fmaxf(acc2B[ot][nt][1] + bv.y, 0.0f);
      float hB2 = fmaxf(acc2B[ot][nt][2] + bv.z, 0.0f);
      float hB3 = fmaxf(acc2B[ot][nt][3] + bv.w, 0.0f);
      p0A = fmaf(hA0, w0.x, fmaf(hA1, w0.y, fmaf(hA2, w0.z, fmaf(hA3, w0.w, p0A))));
      p1A = fmaf(hA0, w1v.x, fmaf(hA1, w1v.y, fmaf(hA2, w1v.z, fmaf(hA3, w1v.w, p1A))));
      p0B = fmaf(hB0, w0.x, fmaf(hB1, w0.y, fmaf(hB2, w0.z, fmaf(hB3, w0.w, p0B))));
      p1B = fmaf(hB0, w1v.x, fmaf(hB1, w1v.y, fmaf(hB2, w1v.z, fmaf(hB3, w1v.w, p1B))));
    }
  }
#pragma unroll
  for (int off = 32; off >= 1; off >>= 1) {
    p0A += __shfl_xor(p0A, off);
    p1A += __shfl_xor(p1A, off);
    p0B += __shfl_xor(p0B, off);
    p1B += __shfl_xor(p1B, off);
  }
  if (lane == 0) {
    red[w * 4 + 0] = p0A;
    red[w * 4 + 1] = p1A;
    red[w * 4 + 2] = p0B;
    red[w * 4 + 3] = p1B;
  }
  __syncthreads();
  if (tid < 4) {
    // tid: bit0 = output j, bit1 = batch
    float s = red[tid] + red[4 + tid] + red[8 + tid] + red[12 + tid] + fc_b[tid & 1];
    out[(b0 + (tid >> 1)) * 2 + (tid & 1)] = s;
  }
}

extern "C" void kernel_launch(void* const* d_in, const int* in_sizes, int n_in,
                              void* d_out, int out_size, void* d_ws, size_t ws_size,
                              hipStream_t stream) {
  const float* x        = (const float*)d_in[0];
  const float* adj      = (const float*)d_in[1];
  const float* adj_bias = (const float*)d_in[2];
  const float* w1       = (const float*)d_in[3];
  const float* b1       = (const float*)d_in[4];
  const float* w2       = (const float*)d_in[5];
  const float* b2       = (const float*)d_in[6];
  const float* fc_w     = (const float*)d_in[7];
  const float* fc_b     = (const float*)d_in[8];
  float* out = (float*)d_out;
  char* ws   = (char*)d_ws;

  prep_kernel<<<17, 256, 0, stream>>>(adj, adj_bias, w1, b1, w2, b2, ws);
  dgcnn_kernel<<<4096, 256, 0, stream>>>(x, ws, fc_w, fc_b, out);
}

// Round 8
// 192.643 us; speedup vs baseline: 1.0720x; 1.0551x over previous
//
#include <hip/hip_runtime.h>

typedef unsigned short u16;
typedef unsigned int u32;
typedef short bf16x8 __attribute__((ext_vector_type(8)));
typedef float f32x4 __attribute__((ext_vector_type(4)));

#define MFMA16(a, b, c) __builtin_amdgcn_mfma_f32_16x16x32_bf16((a), (b), (c), 0, 0, 0)

__device__ __forceinline__ u16 f2bf(float f) {
  u32 u = __builtin_bit_cast(u32, f);
  u += 0x7FFFu + ((u >> 16) & 1u);
  return (u16)(u >> 16);
}
// packed f32x2 -> bf16x2; HW builtin when available, software RNE otherwise
__device__ __forceinline__ u32 pk2bf(float a, float b) {
#if __has_builtin(__builtin_amdgcn_cvt_pk_bf16_f32)
  auto v = __builtin_amdgcn_cvt_pk_bf16_f32(a, b);
  return __builtin_bit_cast(u32, v);
#else
  return (u32)f2bf(a) | ((u32)f2bf(b) << 16);
#endif
}

// ws byte offsets
#define WS_MGF   0         // bf16 [8 jt][64 lane][8 j]      B-frags of M^T   (8192 B)
#define WS_WT1F  8192      // bf16 [8 ot][2 h][4 ks][64][8]  B-frags of Wp1   (65536 B)
#define WS_WT2F  73728     // bf16 [8 mt][4 h][4 ks][64][8]  A-frags of Wp2^T (131072 B)
#define WS_B1    204800    // f32 [128]  bias1 + T0-fold
#define WS_B2    205312    // f32 [128]  bias2 + T0-fold

__global__ void prep_kernel(const float* __restrict__ adj,
                            const float* __restrict__ adj_bias,
                            const float* __restrict__ w1,
                            const float* __restrict__ b1,
                            const float* __restrict__ w2,
                            const float* __restrict__ b2,
                            char* __restrict__ ws) {
  const int tid = threadIdx.x;
  if (blockIdx.x == 0) {
    __shared__ float sa[1024], Ls[1024], L2s[1024], L3s[1024], sdre[32];
    float bias = adj_bias[0];
    for (int i = tid; i < 1024; i += 256) sa[i] = fmaxf(adj[i] + bias, 0.0f);
    __syncthreads();
    if (tid < 32) {
      float s = 0.0f;
      for (int c = 0; c < 32; ++c) s += sa[tid * 32 + c];
      sdre[tid] = 1.0f / sqrtf(s + 1e-5f);
    }
    __syncthreads();
    for (int i = tid; i < 1024; i += 256) {
      int n = i >> 5, c = i & 31;
      Ls[i] = (n == c ? 1.0f : 0.0f) - sdre[n] * sa[i] * sdre[c];
    }
    __syncthreads();
    for (int i = tid; i < 1024; i += 256) {
      int r = i >> 5, c = i & 31;
      float s = 0.0f;
      for (int m = 0; m < 32; ++m) s += Ls[r * 32 + m] * Ls[m * 32 + c];
      L2s[i] = s;
    }
    __syncthreads();
    for (int i = tid; i < 1024; i += 256) {
      int r = i >> 5, c = i & 31;
      float s = 0.0f;
      for (int m = 0; m < 32; ++m) s += L2s[r * 32 + m] * Ls[m * 32 + c];
      L3s[i] = s;
    }
    __syncthreads();
    // M stacked [128x32]: rows 0-31 I, 32-63 L, 64-95 2L^2-I, 96-127 4L^3-3L.
    // B-fragments of M^T: MGf[jt][lane][j] = M[col=jt*16+(lane&15)][k=(lane>>4)*8+j]
    u16* MGf = (u16*)(ws + WS_MGF);
    for (int i = tid; i < 4096; i += 256) {
      int jt = i >> 9, lane = (i >> 3) & 63, j = i & 7;
      int col = jt * 16 + (lane & 15);
      int k = ((lane >> 4) << 3) + j;
      int kk = col >> 5, np = col & 31;
      float v;
      if (kk == 0)      v = (np == k) ? 1.0f : 0.0f;
      else if (kk == 1) v = Ls[np * 32 + k];
      else if (kk == 2) v = 2.0f * L2s[np * 32 + k] - (np == k ? 1.0f : 0.0f);
      else              v = 4.0f * L3s[np * 32 + k] - 3.0f * Ls[np * 32 + k];
      MGf[i] = f2bf(v);
    }
    float* B1 = (float*)(ws + WS_B1);
    float* B2 = (float*)(ws + WS_B2);
    if (tid < 128) {
      float s = b1[tid];
      for (int c = 0; c < 60; ++c) s += w1[(c * 5) * 128 + tid];
      B1[tid] = s;
    } else {
      int o = tid - 128;
      float s = b2[o];
      for (int c = 0; c < 128; ++c) s += w2[(c * 5) * 128 + o];
      B2[o] = s;
    }
  } else {
    u16* WT1F = (u16*)(ws + WS_WT1F);
    u16* WT2F = (u16*)(ws + WS_WT2F);
    int g = (blockIdx.x - 1) * 256 + tid;
    // WT1F bits: j[0:3) lane[3:9) ks[9:11) h[11:12) ot[12:15)
    // element = w1 at kterm=ks, c=h*32+q*8+j (0 if c>=60), o=ot*16+(lane&15)
    for (int i = g; i < 32768; i += 16 * 256) {
      int j = i & 7, lane = (i >> 3) & 63, ks = (i >> 9) & 3;
      int h = (i >> 11) & 1, ot = i >> 12;
      int q = lane >> 4;
      int c = h * 32 + q * 8 + j;
      int o = ot * 16 + (lane & 15);
      WT1F[i] = (c < 60) ? f2bf(w1[(c * 5 + ks + 1) * 128 + o]) : (u16)0;
    }
    // WT2F bits: j[0:3) lane[3:9) ks[9:11) h[11:13) mt[13:16)
    // element = w2 at kterm=ks, c2=h*32+q*8+j, o=mt*16+(lane&15)
    for (int i = g; i < 65536; i += 16 * 256) {
      int j = i & 7, lane = (i >> 3) & 63, ks = (i >> 9) & 3;
      int h = (i >> 11) & 3, mt = i >> 13;
      int q = lane >> 4;
      int c2 = h * 32 + q * 8 + j;
      int o = mt * 16 + (lane & 15);
      WT2F[i] = f2bf(w2[(c2 * 5 + ks + 1) * 128 + o]);
    }
  }
}

// LDS layouts (R6-proven pad-stride family, no swizzle):
//   Xt [64 c][40] u16   (cols n 0..31 + pad, rows 60..63 zeroed)
//   Ht [128 o][36] u16  (cols n 0..31 + pad; overlays Xt region)
//   Y  [32 np][136] u16 per batch (128 kc-chunk cols + pad); kc = kterm*32 + c_local
__global__ __launch_bounds__(256, 4) void dgcnn_kernel(
    const float* __restrict__ x,
    const char* __restrict__ ws,
    const float* __restrict__ fc_w,
    const float* __restrict__ fc_b,
    float* __restrict__ out) {
  __shared__ __align__(16) char arena[35840];
  __shared__ float red[16];
  u16* XtA = (u16*)arena;             // 5120 B
  u16* XtB = (u16*)(arena + 5120);    // 5120 B
  u16* HtA = (u16*)arena;             // 9216 B (after Xt dead)
  u16* HtB = (u16*)(arena + 9216);    // 9216 B
  u16* YA  = (u16*)(arena + 18432);   // 8704 B
  u16* YB  = (u16*)(arena + 27136);   // 8704 B

  const u16* MGf  = (const u16*)(ws + WS_MGF);
  const u16* WT1F = (const u16*)(ws + WS_WT1F);
  const u16* WT2F = (const u16*)(ws + WS_WT2F);
  const float* bias1 = (const float*)(ws + WS_B1);
  const float* bias2 = (const float*)(ws + WS_B2);

  const int tid = threadIdx.x;
  const int w = tid >> 6, lane = tid & 63;
  const int l15 = lane & 15, q = lane >> 4;
  const int b0 = blockIdx.x * 2;
  const f32x4 z4 = {0.0f, 0.0f, 0.0f, 0.0f};

  // M^T B-fragments: wave w covers M^T col tiles 2w, 2w+1 (k-term = w)
  bf16x8 mB0 = *(const bf16x8*)(MGf + ((2 * w + 0) * 64 + lane) * 8);
  bf16x8 mB1 = *(const bf16x8*)(MGf + ((2 * w + 1) * 64 + lane) * 8);

  // ---- stage x^T (both batches); rows 60..63 zeroed ----
  for (int i = tid; i < 160; i += 256) {
    int r = 60 + i / 40, c = i % 40;
    XtA[r * 40 + c] = 0;
    XtB[r * 40 + c] = 0;
  }
  const float* xb = x + (size_t)b0 * 1920;
  for (int i = tid; i < 1920; i += 256) {
    int n = i / 60, c = i - n * 60;
    u32 p = pk2bf(xb[i], xb[1920 + i]);
    XtA[c * 40 + n] = (u16)p;
    XtB[c * 40 + n] = (u16)(p >> 16);
  }
  __syncthreads();

  // ---------------- layer 1: 2 kc-chunks, acc carried in regs ----------------
  f32x4 acc1A[2][2] = {{z4, z4}, {z4, z4}};  // [nt][ot]
  f32x4 acc1B[2][2] = {{z4, z4}, {z4, z4}};
#pragma unroll
  for (int h = 0; h < 2; ++h) {
    // G1: Y[np][w*32 + c_local] = T~[kterm=w][np][c = 32h + c_local]
    {
      f32x4 gA[2][2], gB[2][2];
#pragma unroll
      for (int mtl = 0; mtl < 2; ++mtl) {
        int roff = ((2 * h + mtl) * 16 + l15) * 40 + q * 8;
        bf16x8 aA = *(const bf16x8*)&XtA[roff];
        bf16x8 aB = *(const bf16x8*)&XtB[roff];
        gA[mtl][0] = MFMA16(aA, mB0, z4);
        gA[mtl][1] = MFMA16(aA, mB1, z4);
        gB[mtl][0] = MFMA16(aB, mB0, z4);
        gB[mtl][1] = MFMA16(aB, mB1, z4);
      }
#pragma unroll
      for (int mtl = 0; mtl < 2; ++mtl)
#pragma unroll
        for (int jtl = 0; jtl < 2; ++jtl) {
          int np = jtl * 16 + l15;
          int off = np * 136 + w * 32 + mtl * 16 + q * 4;
          uint2 vA, vB;
          vA.x = pk2bf(gA[mtl][jtl][0], gA[mtl][jtl][1]);
          vA.y = pk2bf(gA[mtl][jtl][2], gA[mtl][jtl][3]);
          vB.x = pk2bf(gB[mtl][jtl][0], gB[mtl][jtl][1]);
          vB.y = pk2bf(gB[mtl][jtl][2], gB[mtl][jtl][3]);
          *(uint2*)&YA[off] = vA;
          *(uint2*)&YB[off] = vB;
        }
    }
    __syncthreads();
    // einsum1 partial over this chunk's 128 kc
#pragma unroll
    for (int ks = 0; ks < 4; ++ks) {
      bf16x8 wfa = *(const bf16x8*)(WT1F + ((((2 * w + 0) * 2 + h) * 4 + ks) * 64 + lane) * 8);
      bf16x8 wfb = *(const bf16x8*)(WT1F + ((((2 * w + 1) * 2 + h) * 4 + ks) * 64 + lane) * 8);
      int yoff = ks * 32 + q * 8;
      bf16x8 a0A = *(const bf16x8*)&YA[l15 * 136 + yoff];
      bf16x8 a1A = *(const bf16x8*)&YA[(16 + l15) * 136 + yoff];
      bf16x8 a0B = *(const bf16x8*)&YB[l15 * 136 + yoff];
      bf16x8 a1B = *(const bf16x8*)&YB[(16 + l15) * 136 + yoff];
      acc1A[0][0] = MFMA16(a0A, wfa, acc1A[0][0]);
      acc1A[0][1] = MFMA16(a0A, wfb, acc1A[0][1]);
      acc1A[1][0] = MFMA16(a1A, wfa, acc1A[1][0]);
      acc1A[1][1] = MFMA16(a1A, wfb, acc1A[1][1]);
      acc1B[0][0] = MFMA16(a0B, wfa, acc1B[0][0]);
      acc1B[0][1] = MFMA16(a0B, wfb, acc1B[0][1]);
      acc1B[1][0] = MFMA16(a1B, wfa, acc1B[1][0]);
      acc1B[1][1] = MFMA16(a1B, wfb, acc1B[1][1]);
    }
    if (h == 0) __syncthreads();  // next G1 rewrites Y
  }
  // bias+relu -> Ht (Xt dead: all Xt reads preceded the last post-G1 barrier)
#pragma unroll
  for (int ot = 0; ot < 2; ++ot) {
    int o = (2 * w + ot) * 16 + l15;
    float bv = bias1[o];
#pragma unroll
    for (int mt = 0; mt < 2; ++mt) {
      int off = o * 36 + mt * 16 + q * 4;
      uint2 vA, vB;
      vA.x = pk2bf(fmaxf(acc1A[mt][ot][0] + bv, 0.0f), fmaxf(acc1A[mt][ot][1] + bv, 0.0f));
      vA.y = pk2bf(fmaxf(acc1A[mt][ot][2] + bv, 0.0f), fmaxf(acc1A[mt][ot][3] + bv, 0.0f));
      vB.x = pk2bf(fmaxf(acc1B[mt][ot][0] + bv, 0.0f), fmaxf(acc1B[mt][ot][1] + bv, 0.0f));
      vB.y = pk2bf(fmaxf(acc1B[mt][ot][2] + bv, 0.0f), fmaxf(acc1B[mt][ot][3] + bv, 0.0f));
      *(uint2*)&HtA[off] = vA;
      *(uint2*)&HtB[off] = vB;
    }
  }
  __syncthreads();

  // ---------------- layer 2: 4 kc-chunks, acc carried in regs ----------------
  f32x4 acc2A[2][2] = {{z4, z4}, {z4, z4}};  // [ot][nt]
  f32x4 acc2B[2][2] = {{z4, z4}, {z4, z4}};
#pragma unroll
  for (int h = 0; h < 4; ++h) {
    // G1: Y[np][w*32 + c2_local] = T~2[kterm=w][np][o = 32h + c2_local]
    {
      f32x4 gA[2][2], gB[2][2];
#pragma unroll
      for (int mtl = 0; mtl < 2; ++mtl) {
        int roff = ((2 * h + mtl) * 16 + l15) * 36 + q * 8;
        bf16x8 aA = *(const bf16x8*)&HtA[roff];
        bf16x8 aB = *(const bf16x8*)&HtB[roff];
        gA[mtl][0] = MFMA16(aA, mB0, z4);
        gA[mtl][1] = MFMA16(aA, mB1, z4);
        gB[mtl][0] = MFMA16(aB, mB0, z4);
        gB[mtl][1] = MFMA16(aB, mB1, z4);
      }
#pragma unroll
      for (int mtl = 0; mtl < 2; ++mtl)
#pragma unroll
        for (int jtl = 0; jtl < 2; ++jtl) {
          int np = jtl * 16 + l15;
          int off = np * 136 + w * 32 + mtl * 16 + q * 4;
          uint2 vA, vB;
          vA.x = pk2bf(gA[mtl][jtl][0], gA[mtl][jtl][1]);
          vA.y = pk2bf(gA[mtl][jtl][2], gA[mtl][jtl][3]);
          vB.x = pk2bf(gB[mtl][jtl][0], gB[mtl][jtl][1]);
          vB.y = pk2bf(gB[mtl][jtl][2], gB[mtl][jtl][3]);
          *(uint2*)&YA[off] = vA;
          *(uint2*)&YB[off] = vB;
        }
    }
    __syncthreads();
    // einsum2 partial (flipped): D[o][n] += Wp2^T[o][chunk kc] @ Y^T[kc][n]
#pragma unroll
    for (int ks = 0; ks < 4; ++ks) {
      bf16x8 wfa = *(const bf16x8*)(WT2F + ((((2 * w + 0) * 4 + h) * 4 + ks) * 64 + lane) * 8);
      bf16x8 wfb = *(const bf16x8*)(WT2F + ((((2 * w + 1) * 4 + h) * 4 + ks) * 64 + lane) * 8);
      int yoff = ks * 32 + q * 8;
      bf16x8 by0A = *(const bf16x8*)&YA[l15 * 136 + yoff];
      bf16x8 by1A = *(const bf16x8*)&YA[(16 + l15) * 136 + yoff];
      bf16x8 by0B = *(const bf16x8*)&YB[l15 * 136 + yoff];
      bf16x8 by1B = *(const bf16x8*)&YB[(16 + l15) * 136 + yoff];
      acc2A[0][0] = MFMA16(wfa, by0A, acc2A[0][0]);
      acc2A[0][1] = MFMA16(wfa, by1A, acc2A[0][1]);
      acc2A[1][0] = MFMA16(wfb, by0A, acc2A[1][0]);
      acc2A[1][1] = MFMA16(wfb, by1A, acc2A[1][1]);
      acc2B[0][0] = MFMA16(wfa, by0B, acc2B[0][0]);
      acc2B[0][1] = MFMA16(wfa, by1B, acc2B[0][1]);
      acc2B[1][0] = MFMA16(wfb, by0B, acc2B[1][0]);
      acc2B[1][1] = MFMA16(wfb, by1B, acc2B[1][1]);
    }
    if (h < 3) __syncthreads();  // next G1 rewrites Y
  }

  // ---- epilogue: bias2+relu in regs, fc directly from accumulators ----
  float p0A = 0.0f, p1A = 0.0f, p0B = 0.0f, p1B = 0.0f;
#pragma unroll
  for (int ot = 0; ot < 2; ++ot) {
    int ob = (2 * w + ot) * 16 + q * 4;  // o base, 4 contiguous per lane
    float4 bv = *(const float4*)&bias2[ob];
#pragma unroll
    for (int nt = 0; nt < 2; ++nt) {
      int n = nt * 16 + l15;
      float4 w0 = *(const float4*)&fc_w[n * 128 + ob];
      float4 w1v = *(const float4*)&fc_w[4096 + n * 128 + ob];
      float hA0 = fmaxf(acc2A[ot][nt][0] + bv.x, 0.0f);
      float hA1 = fmaxf(acc2A[ot][nt][1] + bv.y, 0.0f);
      float hA2 = fmaxf(acc2A[ot][nt][2] + bv.z, 0.0f);
      float hA3 = fmaxf(acc2A[ot][nt][3] + bv.w, 0.0f);
      float hB0 = fmaxf(acc2B[ot][nt][0] + bv.x, 0.0f);
      float hB1 = fmaxf(acc2B[ot][nt][1] + bv.y, 0.0f);
      float hB2 = fmaxf(acc2B[ot][nt][2] + bv.z, 0.0f);
      float hB3 = fmaxf(acc2B[ot][nt][3] + bv.w, 0.0f);
      p0A = fmaf(hA0, w0.x, fmaf(hA1, w0.y, fmaf(hA2, w0.z, fmaf(hA3, w0.w, p0A))));
      p1A = fmaf(hA0, w1v.x, fmaf(hA1, w1v.y, fmaf(hA2, w1v.z, fmaf(hA3, w1v.w, p1A))));
      p0B = fmaf(hB0, w0.x, fmaf(hB1, w0.y, fmaf(hB2, w0.z, fmaf(hB3, w0.w, p0B))));
      p1B = fmaf(hB0, w1v.x, fmaf(hB1, w1v.y, fmaf(hB2, w1v.z, fmaf(hB3, w1v.w, p1B))));
    }
  }
#pragma unroll
  for (int off = 32; off >= 1; off >>= 1) {
    p0A += __shfl_xor(p0A, off);
    p1A += __shfl_xor(p1A, off);
    p0B += __shfl_xor(p0B, off);
    p1B += __shfl_xor(p1B, off);
  }
  if (lane == 0) {
    red[w * 4 + 0] = p0A;
    red[w * 4 + 1] = p1A;
    red[w * 4 + 2] = p0B;
    red[w * 4 + 3] = p1B;
  }
  __syncthreads();
  if (tid < 4) {
    float s = red[tid] + red[4 + tid] + red[8 + tid] + red[12 + tid] + fc_b[tid & 1];
    out[(b0 + (tid >> 1)) * 2 + (tid & 1)] = s;
  }
}

extern "C" void kernel_launch(void* const* d_in, const int* in_sizes, int n_in,
                              void* d_out, int out_size, void* d_ws, size_t ws_size,
                              hipStream_t stream) {
  const float* x        = (const float*)d_in[0];
  const float* adj      = (const float*)d_in[1];
  const float* adj_bias = (const float*)d_in[2];
  const float* w1       = (const float*)d_in[3];
  const float* b1       = (const float*)d_in[4];
  const float* w2       = (const float*)d_in[5];
  const float* b2       = (const float*)d_in[6];
  const float* fc_w     = (const float*)d_in[7];
  const float* fc_b     = (const float*)d_in[8];
  float* out = (float*)d_out;
  char* ws   = (char*)d_ws;

  prep_kernel<<<17, 256, 0, stream>>>(adj, adj_bias, w1, b1, w2, b2, ws);
  dgcnn_kernel<<<4096, 256, 0, stream>>>(x, ws, fc_w, fc_b, out);
}